// Round 5
// baseline (505.752 us; speedup 1.0000x reference)
//
#include <hip/hip_runtime.h>
#include <hip/hip_fp16.h>
#include <math.h>

#define HD 64
#define EPS 1e-5f
#define BSH 9                   // bucket shift: 512 nodes per bucket
#define BSZ 512
#define T1 16384                // edges per tile in k_bucket
// packing: n <= 131072 (2^17) required: packed = (local_dst<<17) | src

__device__ __forceinline__ float atomAddF(float* p, float v) {
    return unsafeAtomicAdd(p, v);   // native global_atomic_add_f32 on gfx950
}

__device__ __forceinline__ void h8_to_f(const uint4 u, float* f) {
    const __half2* h = reinterpret_cast<const __half2*>(&u);
    #pragma unroll
    for (int i = 0; i < 4; ++i) {
        float2 p = __half22float2(h[i]);
        f[2 * i] = p.x; f[2 * i + 1] = p.y;
    }
}

// ---------- CSR build (bucketed counting sort) ----------

__global__ __launch_bounds__(256) void k_bhist(const int* __restrict__ dst,
        int* __restrict__ bcnt, int e) {
    __shared__ int h[256];
    int t = threadIdx.x;
    h[t] = 0;
    __syncthreads();
    for (int i = blockIdx.x * 256 + t; i < e; i += gridDim.x * 256)
        atomicAdd(&h[dst[i] >> BSH], 1);
    __syncthreads();
    if (h[t]) atomicAdd(&bcnt[t], h[t]);
}

__global__ __launch_bounds__(256) void k_bscan(const int* __restrict__ bcnt,
        int* __restrict__ boff, int* __restrict__ gcur,
        int* __restrict__ row_ptr, int nb, int n, int e) {
    __shared__ int sc[256];
    int t = threadIdx.x;
    int v = (t < nb) ? bcnt[t] : 0;
    sc[t] = v;
    __syncthreads();
    int acc = v;
    for (int off = 1; off < 256; off <<= 1) {
        int x = (t >= off) ? sc[t - off] : 0;
        __syncthreads();
        acc += x;
        sc[t] = acc;
        __syncthreads();
    }
    int ex = acc - v;
    boff[t] = ex;                    // thread nb writes boff[nb] = e
    gcur[t] = ex;
    if (t == 0) row_ptr[n] = e;
}

__global__ __launch_bounds__(256) void k_bucket(const int* __restrict__ src,
        const int* __restrict__ dst, int* __restrict__ gcur,
        unsigned* __restrict__ bedges, int e) {
    __shared__ int hist[256];
    __shared__ int base[256];
    int t = threadIdx.x;
    for (int tile = blockIdx.x * T1; tile < e; tile += gridDim.x * T1) {
        int lim = min(e - tile, T1);
        hist[t] = 0;
        __syncthreads();
        for (int j = t; j < lim; j += 256)
            atomicAdd(&hist[dst[tile + j] >> BSH], 1);
        __syncthreads();
        int h = hist[t];
        int mybase = (h > 0) ? atomicAdd(&gcur[t], h) : 0;
        __syncthreads();
        hist[t] = 0;                 // reuse as local cursor
        base[t] = mybase;
        __syncthreads();
        for (int j = t; j < lim; j += 256) {
            int d = dst[tile + j], s = src[tile + j];
            int bk = d >> BSH;
            int loc = atomicAdd(&hist[bk], 1);
            bedges[base[bk] + loc] = ((unsigned)(d & (BSZ - 1)) << 17) | (unsigned)s;
        }
        __syncthreads();
    }
}

__global__ __launch_bounds__(256) void k_build(const unsigned* __restrict__ bedges,
        const int* __restrict__ boff, int* __restrict__ row_ptr,
        int* __restrict__ csr, float* __restrict__ dinv, int n) {
    __shared__ int hist[BSZ];
    __shared__ int cur[BSZ];
    __shared__ int sc[256];
    int b = blockIdx.x, t = threadIdx.x;
    int nodebase = b << BSH;
    int beg = boff[b], end = boff[b + 1];
    hist[t] = 0; hist[t + 256] = 0;
    __syncthreads();
    for (int j = beg + t; j < end; j += 256)
        atomicAdd(&hist[bedges[j] >> 17], 1);
    __syncthreads();
    int a0 = hist[2 * t], a1 = hist[2 * t + 1];
    int psum = a0 + a1;
    sc[t] = psum;
    __syncthreads();
    int acc = psum;
    for (int off = 1; off < 256; off <<= 1) {
        int x = (t >= off) ? sc[t - off] : 0;
        __syncthreads();
        acc += x;
        sc[t] = acc;
        __syncthreads();
    }
    int excl = acc - psum;           // exclusive over node pairs
    int e0 = beg + excl, e1 = beg + excl + a0;
    cur[2 * t] = e0;
    cur[2 * t + 1] = e1;
    int n0 = nodebase + 2 * t, n1 = nodebase + 2 * t + 1;
    if (n0 < n) { row_ptr[n0] = e0; dinv[n0] = rsqrtf((float)(a0 + 1)); }
    if (n1 < n) { row_ptr[n1] = e1; dinv[n1] = rsqrtf((float)(a1 + 1)); }
    __syncthreads();
    for (int j = beg + t; j < end; j += 256) {
        unsigned p = bedges[j];
        int pos = atomicAdd(&cur[p >> 17], 1);
        csr[pos] = (int)(p & 0x1FFFFu);
    }
}

// ---------- layer compute ----------
// A planes: plane p holds channels [p*32, p*32+32), row = 32 halves = 64B.
// A[p*(n<<5) + (n<<5)... wait per-node: Aplane_p[n][cc] at offset p*(N<<5) + (n<<5) + cc

// A[n][c] = half( dinv[n] * sum_k x[n][k]*W0[k][c] ), written into 2 planes
__global__ __launch_bounds__(256) void k_lin0(const float* __restrict__ x,
        const float* __restrict__ W0, const float* __restrict__ dinv,
        __half* __restrict__ A, int n_nodes) {
    __shared__ float w[4 * HD];
    int t = threadIdx.x;
    w[t] = W0[t];
    __syncthreads();
    int n = blockIdx.x * 4 + (t >> 6);
    int c = t & 63;
    if (n >= n_nodes) return;
    float x0 = x[n * 4 + 0], x1 = x[n * 4 + 1], x2 = x[n * 4 + 2], x3 = x[n * 4 + 3];
    float v = x0 * w[c] + x1 * w[64 + c] + x2 * w[128 + c] + x3 * w[192 + c];
    size_t pbase = (size_t)(c >> 5) * ((size_t)n_nodes << 5);
    A[pbase + ((size_t)n << 5) + (c & 31)] = __float2half(v * dinv[n]);
}

// CSR gather-aggregate, plane-split (64B rows, 16 edges per wave-instr, 2-deep):
// B[n][c] = dinv[n]*(A[n][c] + sum_in A[src][c]) + bias[c]; stats accumulated
__global__ __launch_bounds__(256) void k_aggr(const int* __restrict__ row_ptr,
        const int* __restrict__ csr, const __half* __restrict__ A,
        const float* __restrict__ dinv, const float* __restrict__ bias,
        float* __restrict__ B, float* __restrict__ stats, int n_nodes, int half_grid) {
    int t = threadIdx.x;
    int lane = t & 63, wv = t >> 6;
    int eg = lane >> 2, cg = lane & 3;     // edge slot 0..15, channel group 0..3
    int bid = blockIdx.x;
    int xcd = bid & 7;
    int plane = xcd >> 2;                  // XCD 0-3 -> plane 0, XCD 4-7 -> plane 1
    int prank = (bid >> 3) * 4 + (xcd & 3);
    const __half* Ap = A + (size_t)plane * ((size_t)n_nodes << 5);
    int cbase = (plane << 5) + (cg << 3);  // global channel base 0..56
    float st[8], st2[8];
    #pragma unroll
    for (int k = 0; k < 8; ++k) { st[k] = 0.f; st2[k] = 0.f; }
    for (int n = prank * 4 + wv; n < n_nodes; n += half_grid * 4) {
        int beg = __builtin_nontemporal_load(&row_ptr[n]);
        int end = __builtin_nontemporal_load(&row_ptr[n + 1]);
        float acc[8];
        {   // self-loop term (only eg==0 keeps it)
            uint4 u = *reinterpret_cast<const uint4*>(Ap + ((size_t)n << 5) + (cg << 3));
            float f[8]; h8_to_f(u, f);
            float m = (eg == 0) ? 1.f : 0.f;
            #pragma unroll
            for (int k = 0; k < 8; ++k) acc[k] = m * f[k];
        }
        int j = beg;
        for (; j + 32 <= end; j += 32) {   // 2 independent 16-edge gathers in flight
            int s0 = __builtin_nontemporal_load(&csr[j + eg]);
            int s1 = __builtin_nontemporal_load(&csr[j + 16 + eg]);
            uint4 u0 = *reinterpret_cast<const uint4*>(Ap + ((size_t)s0 << 5) + (cg << 3));
            uint4 u1 = *reinterpret_cast<const uint4*>(Ap + ((size_t)s1 << 5) + (cg << 3));
            float f0[8], f1[8];
            h8_to_f(u0, f0); h8_to_f(u1, f1);
            #pragma unroll
            for (int k = 0; k < 8; ++k) acc[k] += f0[k] + f1[k];
        }
        for (; j < end; j += 16) {
            int idx = j + eg;
            if (idx < end) {
                int s = __builtin_nontemporal_load(&csr[idx]);
                uint4 u = *reinterpret_cast<const uint4*>(Ap + ((size_t)s << 5) + (cg << 3));
                float f[8]; h8_to_f(u, f);
                #pragma unroll
                for (int k = 0; k < 8; ++k) acc[k] += f[k];
            }
        }
        // reduce over edge slots: eg bits are lane bits 2,3,4,5
        #pragma unroll
        for (int d = 4; d < 64; d <<= 1) {
            #pragma unroll
            for (int k = 0; k < 8; ++k) acc[k] += __shfl_xor(acc[k], d, 64);
        }
        if (eg == 0) {
            float dv = dinv[n];
            float v[8];
            #pragma unroll
            for (int k = 0; k < 8; ++k) {
                v[k] = dv * acc[k] + bias[cbase + k];
                st[k] += v[k]; st2[k] += v[k] * v[k];
            }
            float4* bp = reinterpret_cast<float4*>(B + ((size_t)n << 6) + cbase);
            bp[0] = make_float4(v[0], v[1], v[2], v[3]);
            bp[1] = make_float4(v[4], v[5], v[6], v[7]);
        }
    }
    __shared__ float ls[4][32], ls2[4][32];
    if (eg == 0) {
        #pragma unroll
        for (int k = 0; k < 8; ++k) {
            ls[wv][(cg << 3) + k] = st[k];
            ls2[wv][(cg << 3) + k] = st2[k];
        }
    }
    __syncthreads();
    if (t < 32) {
        float a = ls[0][t] + ls[1][t] + ls[2][t] + ls[3][t];
        float a2 = ls2[0][t] + ls2[1][t] + ls2[2][t] + ls2[3][t];
        atomAddF(&stats[(plane << 5) + t], a);
        atomAddF(&stats[64 + (plane << 5) + t], a2);
    }
}

// A(half planes) <- dinv[n] * (relu(bn(B)) @ W1)   (BN0+ReLU fused into row staging)
__global__ __launch_bounds__(256) void k_lin1(const float* __restrict__ B,
        const float* __restrict__ W, const float* __restrict__ dinv,
        const float* __restrict__ stats, const float* __restrict__ g,
        const float* __restrict__ be, __half* __restrict__ A, int n_nodes) {
    __shared__ float w[HD * HD];
    __shared__ float rows[4][HD];
    int t = threadIdx.x;
    for (int i = t; i < HD * HD; i += 256) w[i] = W[i];
    int wv = t >> 6, c = t & 63;
    float inv_n = 1.0f / (float)n_nodes;
    float mu = stats[c] * inv_n;
    float var = stats[64 + c] * inv_n - mu * mu;
    float sc = g[c] * rsqrtf(var + EPS);
    float sh = be[c] - mu * sc;
    size_t pbase = (size_t)(c >> 5) * ((size_t)n_nodes << 5);
    int cc = c & 31;
    int ngroups = (n_nodes + 3) >> 2;
    for (int gidx = blockIdx.x; gidx < ngroups; gidx += gridDim.x) {
        __syncthreads();
        int n = gidx * 4 + wv;
        float rv = (n < n_nodes) ? fmaxf(sc * B[((size_t)n << 6) + c] + sh, 0.f) : 0.f;
        rows[wv][c] = rv;
        __syncthreads();
        if (n < n_nodes) {
            float acc = 0.f;
            #pragma unroll
            for (int k = 0; k < HD; k++) acc = fmaf(rows[wv][k], w[k * 64 + c], acc);
            A[pbase + ((size_t)n << 5) + cc] = __float2half(acc * dinv[n]);
        }
    }
}

// fused: h = relu(bn1(B)); out = sigmoid(relu(relu(h@Wm0+bm0)@Wm1+bm1)@Wm2+bm2)
__global__ __launch_bounds__(64) void k_mlp(const float* __restrict__ B,
        const float* __restrict__ stats, const float* __restrict__ g,
        const float* __restrict__ be,
        const float* __restrict__ Wm0, const float* __restrict__ bm0,
        const float* __restrict__ Wm1, const float* __restrict__ bm1,
        const float* __restrict__ Wm2, const float* __restrict__ bm2,
        float* __restrict__ out, int n_nodes) {
    __shared__ float rows[64][65];
    int t = threadIdx.x;
    float inv_n = 1.0f / (float)n_nodes;
    float mu = stats[t] * inv_n;
    float var = stats[64 + t] * inv_n - mu * mu;
    float sc = g[t] * rsqrtf(var + EPS);
    float sh = be[t] - mu * sc;
    int nbase = blockIdx.x * 64;
    #pragma unroll 4
    for (int r = 0; r < 64; r++) {
        int nn = nbase + r;
        rows[r][t] = (nn < n_nodes) ? fmaxf(sc * B[((size_t)nn << 6) + t] + sh, 0.f) : 0.f;
    }
    __syncthreads();
    int n = nbase + t;
    if (n >= n_nodes) return;

    float a1[64];
    #pragma unroll
    for (int cc = 0; cc < 4; ++cc) {
        float acc[16];
        #pragma unroll
        for (int j = 0; j < 16; ++j) acc[j] = bm0[cc * 16 + j];
        for (int k = 0; k < 64; ++k) {
            float hv = rows[t][k];
            #pragma unroll
            for (int j = 0; j < 16; ++j)
                acc[j] = fmaf(hv, Wm0[k * 64 + cc * 16 + j], acc[j]);
        }
        #pragma unroll
        for (int j = 0; j < 16; ++j) a1[cc * 16 + j] = fmaxf(acc[j], 0.f);
    }
    #pragma unroll
    for (int k = 0; k < 64; ++k) rows[t][k] = a1[k];

    float a2[32];
    #pragma unroll
    for (int cc = 0; cc < 2; ++cc) {
        float acc[16];
        #pragma unroll
        for (int j = 0; j < 16; ++j) acc[j] = bm1[cc * 16 + j];
        for (int k = 0; k < 64; ++k) {
            float hv = rows[t][k];
            #pragma unroll
            for (int j = 0; j < 16; ++j)
                acc[j] = fmaf(hv, Wm1[k * 32 + cc * 16 + j], acc[j]);
        }
        #pragma unroll
        for (int j = 0; j < 16; ++j) a2[cc * 16 + j] = fmaxf(acc[j], 0.f);
    }
    float z = bm2[0];
    #pragma unroll
    for (int k = 0; k < 32; ++k) z = fmaf(a2[k], Wm2[k], z);
    out[n] = 1.0f / (1.0f + __expf(-z));
}

extern "C" void kernel_launch(void* const* d_in, const int* in_sizes, int n_in,
                              void* d_out, int out_size, void* d_ws, size_t ws_size,
                              hipStream_t stream) {
    const float* x   = (const float*)d_in[0];
    const int*   src = (const int*)d_in[1];
    const int*   dst = (const int*)d_in[2];
    const float* W0  = (const float*)d_in[3];
    const float* b0  = (const float*)d_in[4];
    const float* W1  = (const float*)d_in[5];
    const float* b1  = (const float*)d_in[6];
    const float* g0  = (const float*)d_in[7];
    const float* be0 = (const float*)d_in[8];
    const float* g1  = (const float*)d_in[9];
    const float* be1 = (const float*)d_in[10];
    const float* Wm0 = (const float*)d_in[11];
    const float* bm0 = (const float*)d_in[12];
    const float* Wm1 = (const float*)d_in[13];
    const float* bm1 = (const float*)d_in[14];
    const float* Wm2 = (const float*)d_in[15];
    const float* bm2 = (const float*)d_in[16];

    int n = in_sizes[0] / 4;
    int e = in_sizes[1];
    float* out = (float*)d_out;

    char* ws = (char*)d_ws;
    auto alignup = [](size_t v) { return (v + 255) & ~(size_t)255; };
    size_t o = 0;
    int*      bcnt    = (int*)(ws + o);      o += alignup(256 * 4);
    int*      boff    = (int*)(ws + o);      o += alignup(257 * 4);
    int*      gcur    = (int*)(ws + o);      o += alignup(256 * 4);
    float*    stats   = (float*)(ws + o);    o += alignup(256 * 4);
    int*      row_ptr = (int*)(ws + o);      o += alignup((size_t)(n + 1) * 4);
    float*    dinv    = (float*)(ws + o);    o += alignup((size_t)n * 4);
    unsigned* bedges  = (unsigned*)(ws + o); o += alignup((size_t)e * 4);
    int*      csr     = (int*)(ws + o);      o += alignup((size_t)e * 4);
    __half*   A       = (__half*)(ws + o);   o += alignup((size_t)n * 64 * 2);
    float*    B       = (float*)(ws + o);

    int nb     = (n + BSZ - 1) >> BSH;        // 196 buckets for n=100k (requires n<=131072)
    int gN4    = (n + 3) / 4;
    int ntiles = (e + T1 - 1) / T1;
    int gMLP   = (n + 63) / 64;
    int gAGG   = 4096;                        // multiple of 8; 2048 blocks per plane

    hipMemsetAsync(bcnt, 0, 256 * 4, stream);
    hipMemsetAsync(stats, 0, 256 * 4, stream);

    // ---- CSR build (bucketed, once, reused by both layers) ----
    k_bhist<<<512, 256, 0, stream>>>(dst, bcnt, e);
    k_bscan<<<1, 256, 0, stream>>>(bcnt, boff, gcur, row_ptr, nb, n, e);
    k_bucket<<<ntiles, 256, 0, stream>>>(src, dst, gcur, bedges, e);
    k_build<<<nb, 256, 0, stream>>>(bedges, boff, row_ptr, csr, dinv, n);

    // ---- layer 1 ----
    k_lin0<<<gN4, 256, 0, stream>>>(x, W0, dinv, A, n);
    k_aggr<<<gAGG, 256, 0, stream>>>(row_ptr, csr, A, dinv, b0, B, stats, n, gAGG / 2);

    // ---- layer 2 (BN0+ReLU fused into lin1) ----
    k_lin1<<<2048, 256, 0, stream>>>(B, W1, dinv, stats, g0, be0, A, n);
    k_aggr<<<gAGG, 256, 0, stream>>>(row_ptr, csr, A, dinv, b1, B, stats + 128, n, gAGG / 2);

    // ---- MLP head (BN1+ReLU fused) ----
    k_mlp<<<gMLP, 64, 0, stream>>>(B, stats + 128, g1, be1,
                                   Wm0, bm0, Wm1, bm1, Wm2, bm2, out, n);
}